// Round 6
// baseline (292.037 us; speedup 1.0000x reference)
//
#include <hip/hip_runtime.h>
#include <math.h>

// QuantumIntegrator: r_embed [B=4, S=4096, 2] float32, dt [4] float32.
// Outputs (flat float32): r_final [4,4096,2] then score [4,4096,4096].
//
// R6 structure: split reduction from score write.
//   k_red1: per-row triangular reduction over r -> k1, r_mid, s1, inv (ws).
//   k_red2: per-row reduction over r_mid -> k2 -> r_final.
//   k_score: 16-row x 1024-col tiles; 4 cols/thread held in registers,
//            reused across 16 rows; row params via uniform scalar loads.
//            Regular stores (R5 post-mortem: NT stores cost +14 us).
// 268 MB fp32 score write floor ~41 us @ 6.6 TB/s.

#define S_LEN 4096
#define ROWS  16384   // B*S with B=4 (fixed by setup_inputs)
#define BLK   256
#define TR    16      // rows per score tile
#define TC    1024    // cols per score tile (256 thr x 4)
#define EPSF  1e-6f
#define RATE  0.01f
#define MINR  0.1f
#define MAXR  2.0f

typedef float vf4 __attribute__((ext_vector_type(4)));

// In-wave reduction of 3 floats; result valid in lane 0.
__device__ __forceinline__ void wave_red3(float &a, float &b, float &c) {
    #pragma unroll
    for (int off = 32; off > 0; off >>= 1) {
        a += __shfl_down(a, off);
        b += __shfl_down(b, off);
        c += __shfl_down(c, off);
    }
}

// ws layout (floats):
//   [0,       2*ROWS) r_mid (x,y)
//   [2*ROWS,  4*ROWS) k1    (x,y)
//   [4*ROWS,  5*ROWS) s1    (sum of normalized score row)
//   [5*ROWS,  6*ROWS) inv   (1/max(denom,eps))

__global__ __launch_bounds__(BLK) void k_red1(
    const float2* __restrict__ r_in,
    const float* __restrict__ dt_in,
    float* __restrict__ ws)
{
    const int lane = threadIdx.x & 63;
    const int row  = (blockIdx.x << 2) + (threadIdx.x >> 6);   // wave-per-row
    const int b = row >> 12;
    const int s = row & (S_LEN - 1);
    const float2* rb  = r_in + ((size_t)b << 12);
    const vf4*    rb4 = (const vf4*)rb;
    const float2  rs  = rb[s];

    float dsum = 0.f, nx = 0.f, ny = 0.f;
    for (int i = lane; 2*i <= s; i += 64) {
        vf4 p = rb4[i];
        float d0 = fmaxf(rs.x * p.x + rs.y * p.y, 0.f);   // t = 2i <= s
        dsum += d0; nx = fmaf(d0, p.x, nx); ny = fmaf(d0, p.y, ny);
        if (2*i + 1 <= s) {
            float d1 = fmaxf(rs.x * p.z + rs.y * p.w, 0.f);
            dsum += d1; nx = fmaf(d1, p.z, nx); ny = fmaf(d1, p.w, ny);
        }
    }
    wave_red3(dsum, nx, ny);
    if (lane == 0) {
        const float D   = dsum;
        const float inv = 1.f / fmaxf(D, EPSF);
        const float dtb = dt_in[b];
        float k1x = dtb * nx * inv;
        float k1y = dtb * ny * inv;
        if (!isfinite(k1x)) k1x = 0.f;
        if (!isfinite(k1y)) k1y = 0.f;
        float rmx = rs.x + k1x, rmy = rs.y + k1y;
        if (!isfinite(rmx)) rmx = rs.x;
        if (!isfinite(rmy)) rmy = rs.y;
        ws[2*row]            = rmx;  ws[2*row+1]          = rmy;
        ws[2*ROWS + 2*row]   = k1x;  ws[2*ROWS + 2*row+1] = k1y;
        ws[4*ROWS + row]     = D * inv;
        ws[5*ROWS + row]     = inv;
    }
}

__global__ __launch_bounds__(BLK) void k_score(
    const float2* __restrict__ r_in,
    const float* __restrict__ ws,
    float* __restrict__ score_out)
{
    const int ct   = blockIdx.x;              // col tile: 0..3
    const int row0 = blockIdx.y * TR;         // global row base (tile within batch)
    const int b    = row0 >> 12;
    const int s0   = row0 & (S_LEN - 1);
    const int t0   = ct << 10;
    const int c    = t0 + (threadIdx.x << 2); // this thread's first column
    float* out0 = score_out + (size_t)row0 * S_LEN + c;

    // Fast path: whole tile strictly above the diagonal -> zeros.
    if (t0 > s0 + TR - 1) {
        const vf4 z = {0.f, 0.f, 0.f, 0.f};
        #pragma unroll
        for (int rr = 0; rr < TR; rr++)
            *(vf4*)(out0 + (size_t)rr * S_LEN) = z;
        return;
    }

    const vf4* rb4 = (const vf4*)(r_in + ((size_t)b << 12));
    const vf4 p01 = rb4[c >> 1];        // cols c, c+1
    const vf4 p23 = rb4[(c >> 1) + 1];  // cols c+2, c+3
    const float2* rrow = r_in;          // uniform row loads
    const float*  invw = ws + 5 * ROWS;

    const bool nomask = (t0 + TC - 1) <= s0;  // tile fully below diagonal
    #pragma unroll
    for (int rr = 0; rr < TR; rr++) {
        const float2 rv = rrow[row0 + rr];    // uniform -> s_load
        const float  iv = invw[row0 + rr];
        const float sx = rv.x * iv, sy = rv.y * iv;  // relu(d)*iv == relu(d*iv), iv>0
        vf4 v;
        v.x = fmaxf(sx * p01.x + sy * p01.y, 0.f);
        v.y = fmaxf(sx * p01.z + sy * p01.w, 0.f);
        v.z = fmaxf(sx * p23.x + sy * p23.y, 0.f);
        v.w = fmaxf(sx * p23.z + sy * p23.w, 0.f);
        if (!nomask) {
            const int s = s0 + rr;
            v.x = (c     <= s) ? v.x : 0.f;
            v.y = (c + 1 <= s) ? v.y : 0.f;
            v.z = (c + 2 <= s) ? v.z : 0.f;
            v.w = (c + 3 <= s) ? v.w : 0.f;
        }
        *(vf4*)(out0 + (size_t)rr * S_LEN) = v;
    }
}

__global__ __launch_bounds__(BLK) void k_red2(
    const float2* __restrict__ r_in,
    const float* __restrict__ dt_in,
    const float* __restrict__ ws,
    float* __restrict__ rfinal_out)               // fp32, [ROWS, 2]
{
    const int lane = threadIdx.x & 63;
    const int row  = (blockIdx.x << 2) + (threadIdx.x >> 6);
    const int b = row >> 12;
    const int s = row & (S_LEN - 1);
    const float2* rm  = ((const float2*)ws) + ((size_t)b << 12);
    const vf4*    rm4 = (const vf4*)rm;
    const float2  rs  = rm[s];

    float dsum = 0.f, nx = 0.f, ny = 0.f;
    for (int i = lane; 2*i <= s; i += 64) {
        vf4 p = rm4[i];
        float d0 = fmaxf(rs.x * p.x + rs.y * p.y, 0.f);
        dsum += d0; nx = fmaf(d0, p.x, nx); ny = fmaf(d0, p.y, ny);
        if (2*i + 1 <= s) {
            float d1 = fmaxf(rs.x * p.z + rs.y * p.w, 0.f);
            dsum += d1; nx = fmaf(d1, p.z, nx); ny = fmaf(d1, p.w, ny);
        }
    }
    wave_red3(dsum, nx, ny);
    if (lane == 0) {
        const float dc = fmaxf(dsum, EPSF);
        const float dtb = dt_in[b];
        float k2x = dtb * nx / dc;
        float k2y = dtb * ny / dc;
        if (!isfinite(k2x)) k2x = 0.f;
        if (!isfinite(k2y)) k2y = 0.f;
        const float2 r0 = r_in[row];
        const float k1x = ws[2*ROWS + 2*row], k1y = ws[2*ROWS + 2*row+1];
        const float rnx = r0.x + 0.5f * (k1x + k2x);
        const float rny = r0.y + 0.5f * (k1y + k2y);
        const float nr = fmaxf(sqrtf(rnx*rnx + rny*rny), EPSF);
        const float ar = fminf(fmaxf(nr + ws[4*ROWS + row] * RATE, MINR), MAXR);
        const float sc = ar / nr;
        float fx = rnx * sc, fy = rny * sc;
        if (!isfinite(fx)) fx = r0.x;
        if (!isfinite(fy)) fy = r0.y;
        rfinal_out[2*row]   = fx;
        rfinal_out[2*row+1] = fy;
    }
}

extern "C" void kernel_launch(void* const* d_in, const int* in_sizes, int n_in,
                              void* d_out, int out_size, void* d_ws, size_t ws_size,
                              hipStream_t stream) {
    const float2* r_in  = (const float2*)d_in[0];   // fp32 [4,4096,2]
    const float*  dt_in = (const float*)d_in[1];    // fp32 [4]
    float* out = (float*)d_out;
    float* ws  = (float*)d_ws;

    // d_out: first ROWS*2 floats = r_final, then ROWS*S_LEN floats = score.
    float* rfinal_out = out;
    float* score_out  = out + (size_t)2 * ROWS;

    hipLaunchKernelGGL(k_red1, dim3(ROWS / 4), dim3(BLK), 0, stream,
                       r_in, dt_in, ws);
    hipLaunchKernelGGL(k_score, dim3(S_LEN / TC, ROWS / TR), dim3(BLK), 0, stream,
                       r_in, ws, score_out);
    hipLaunchKernelGGL(k_red2, dim3(ROWS / 4), dim3(BLK), 0, stream,
                       r_in, dt_in, ws, rfinal_out);
}